// Round 2
// baseline (11597.142 us; speedup 1.0000x reference)
//
#include <hip/hip_runtime.h>

// RecognitionODERNN: B=256,T=96,OBS=64,LATENT=256,HID=512, 3 RK4 substeps/interval.
// 16 persistent workgroups (one per CU), 16 batch rows each, no inter-WG sync.
// fp16 MFMA 16x16x32, fp32 accumulate, fp32 master state; accurate tanh (~1 ulp).
// Precision (R1-R6): state hi/lo fp16, RNN weights hi+lo fp16 streamed, RNN
// hidden hi/lo, accurate tanh => absmax 2.0 vs threshold 7.24.
// R10 (perf): runtime 12-step RK4 loop + single rnn call site => hot body fits L1I.
// R11 (perf): WG 512->1024 (4 waves/SIMD). NEUTRAL (6707->6652): waves run in
// lockstep between 2 barriers/eval, extra TLP just queues deeper on the one
// shared LDS pipe; bank-conflict counter doubled with wave count.
// R12 (perf): cut shared-LDS-pipe work + dependent-chain depth:
//   (a) W2 fully register/AGPR resident (w2f[16]) — sW2 LDS region, its staging,
//       and 112 LDS reads/eval deleted; LDS now 54 KB total.
//   (b) accumulator splitting: GEMM1 hi/lo chains separate, GEMM2 even/odd ks,
//       RNN 3-way — dependent MFMA chains 16->8/10 deep.
//   (c) RNN hidden-lo de-aliased into its own LDS plane: RNN barriers 5->3.

#define TT 96
#define OBS 64
#define LATENT 256
#define HID 512

typedef _Float16 h8 __attribute__((ext_vector_type(8)));
typedef _Float16 h2 __attribute__((ext_vector_type(2)));
typedef float f4 __attribute__((ext_vector_type(4)));

// ws layout (fp16 element offsets), all regions in MFMA B-fragment order.
#define OFF_W1F   0u        // [w(8)][t(4)][ks(8)][lane(64)][j(8)]   W1 256x512 hi
#define OFF_W2V   131072u   // [w(8)][t2(2)][ks(8)][lane][j]         W2 k=0..255 hi
#define OFF_W2L   196608u   // [ks2(8)][w(8)][t2(2)][lane][j]        W2 k=256..511 hi
#define OFF_WR1   262144u   // [ks(10)][w(8)][t(4)][lane][j]         Wr1 320x512 hi
#define OFF_WR2   425984u   // [ks(16)][w(8)][t2(2)][lane][j]        Wr2 512x256 hi
#define OFF_WR1L  557056u   // Wr1 lo plane (same geometry as hi)
#define OFF_WR2L  720896u   // Wr2 lo plane

// LDS layout (bytes): activations only (W2 now fully in registers).
#define XSTR      648       // sX rows: [0,256) s-hi, [256,320) obs-hi,
                            //          [320,576) s-lo, [576,640) obs-lo, pad 8
#define HSTR      520       // sH / sHL: 16 x 520 fp16 rows (512 + pad 8)
#define LDS_H     (16*XSTR*2)                    // 20736
#define LDS_HL    (LDS_H + 16*HSTR*2)            // 37376
#define LDS_TOTAL (LDS_HL + 16*HSTR*2)           // 54016

__global__ void prep_kernel(const float* __restrict__ W1, const float* __restrict__ W2,
                            const float* __restrict__ Wr1, const float* __restrict__ Wr2,
                            _Float16* __restrict__ ws) {
  unsigned f = blockIdx.x * 256u + threadIdx.x;   // fragment id, 106496 total
  if (f >= 106496u) return;
  bool lo = false;
  unsigned fe = f, dstv = 0;
  if (f >= 90112u)      { lo = true; fe = f - 90112u + 53248u; dstv = OFF_WR2L + (f - 90112u) * 8u; }
  else if (f >= 69632u) { lo = true; fe = f - 69632u + 32768u; dstv = OFF_WR1L + (f - 69632u) * 8u; }
  const float* src;
  unsigned k0, n, ldn, dst;
  if (fe < 16384u) {                       // W1 frags
    unsigned ln = fe & 63u, ks = (fe >> 6) & 7u, t = (fe >> 9) & 3u, w = fe >> 11;
    n = w * 64u + t * 16u + (ln & 15u);
    k0 = ks * 32u + (ln >> 4) * 8u;
    src = W1; ldn = HID; dst = OFF_W1F + fe * 8u;
  } else if (fe < 24576u) {                // W2 k=0..255
    unsigned f2 = fe - 16384u;
    unsigned ln = f2 & 63u, ks = (f2 >> 6) & 7u, t2 = (f2 >> 9) & 1u, w = f2 >> 10;
    n = w * 32u + t2 * 16u + (ln & 15u);
    k0 = ks * 32u + (ln >> 4) * 8u;
    src = W2; ldn = LATENT; dst = OFF_W2V + f2 * 8u;
  } else if (fe < 32768u) {                // W2 k=256..511
    unsigned f3 = fe - 24576u;
    unsigned ln = f3 & 63u, t2 = (f3 >> 6) & 1u, w = (f3 >> 7) & 7u, ks2 = f3 >> 10;
    n = w * 32u + t2 * 16u + (ln & 15u);
    k0 = (ks2 + 8u) * 32u + (ln >> 4) * 8u;
    src = W2; ldn = LATENT; dst = OFF_W2L + f3 * 8u;
  } else if (fe < 53248u) {                // Wr1 (streamed)
    unsigned f4_ = fe - 32768u;
    unsigned ln = f4_ & 63u, t = (f4_ >> 6) & 3u, w = (f4_ >> 8) & 7u, ks = f4_ >> 11;
    n = w * 64u + t * 16u + (ln & 15u);
    k0 = ks * 32u + (ln >> 4) * 8u;
    src = Wr1; ldn = HID; dst = OFF_WR1 + f4_ * 8u;
  } else {                                 // Wr2 (streamed)
    unsigned f5 = fe - 53248u;
    unsigned ln = f5 & 63u, t2 = (f5 >> 6) & 1u, w = (f5 >> 7) & 7u, ks = f5 >> 10;
    n = w * 32u + t2 * 16u + (ln & 15u);
    k0 = ks * 32u + (ln >> 4) * 8u;
    src = Wr2; ldn = LATENT; dst = OFF_WR2 + f5 * 8u;
  }
  if (lo) dst = dstv;
  h8 v;
#pragma unroll
  for (int j = 0; j < 8; ++j) {
    float w = src[(k0 + (unsigned)j) * ldn + n];
    _Float16 hi = (_Float16)w;
    v[j] = lo ? (_Float16)(w - (float)hi) : hi;
  }
  *(h8*)(ws + dst) = v;
}

// ~1 ulp tanh: Taylor (odd, to x^9) for |x|<0.25; exp2 + IEEE division above.
__device__ __forceinline__ float tanh_acc(float x) {
  float ax = __builtin_fabsf(x);
  float e = __builtin_amdgcn_exp2f(ax * -2.885390043258667f);   // e^-2x
  float tl = (1.0f - e) / (1.0f + e);        // IEEE div (no fast-math)
  float x2 = ax * ax;
  float p = -17.0f/315.0f + x2 * (62.0f/2835.0f);
  p = 2.0f/15.0f + x2 * p;
  p = -1.0f/3.0f + x2 * p;
  float ts = ax + (ax * x2) * p;
  float r = ax < 0.25f ? ts : tl;
  return __builtin_copysignf(r, x);
}

__global__ __launch_bounds__(1024)
__attribute__((amdgpu_waves_per_eu(4, 4)))
void ode_main(
    const float* __restrict__ dataset, const float* __restrict__ ts,
    const float* __restrict__ b1g, const float* __restrict__ b2g,
    const float* __restrict__ br1g, const float* __restrict__ br2g,
    const _Float16* __restrict__ ws, float* __restrict__ out) {
  extern __shared__ char smem[];
  _Float16* sX  = (_Float16*)(smem);
  _Float16* sH  = (_Float16*)(smem + LDS_H);
  _Float16* sHL = (_Float16*)(smem + LDS_HL);

  const int tid = threadIdx.x;
  const int wv = tid >> 6, ln = tid & 63;       // wv in [0,16)
  const int q = ln >> 4, c16 = ln & 15;
  const int b0 = blockIdx.x * 16;

  // ---- resident weight fragments: W1 all (16 frags/wave), W2 all (16/wave) ----
  // wave wv owns HID cols [wv*32, wv*32+32) (t in {0,1}) and LATENT cols
  // [wv*16, wv*16+16).
  h8 w1f[2][8], w2f[16];
#pragma unroll
  for (int t = 0; t < 2; ++t)
#pragma unroll
    for (int ks = 0; ks < 8; ++ks)
      w1f[t][ks] = *(const h8*)(ws + OFF_W1F + (unsigned)((((wv*2 + t)*8 + ks)*64 + ln) * 8));
#pragma unroll
  for (int ks = 0; ks < 8; ++ks)
    w2f[ks] = *(const h8*)(ws + OFF_W2V + (unsigned)(((wv*8 + ks)*64 + ln) * 8));
#pragma unroll
  for (int ks = 8; ks < 16; ++ks)
    w2f[ks] = *(const h8*)(ws + OFF_W2L + (unsigned)((((ks - 8)*1024) + wv*64 + ln) * 8));

  // ---- biases ----
  float b1r[2], br1r[2], b2r, br2r;
#pragma unroll
  for (int t = 0; t < 2; ++t) {
    int col = wv * 32 + t * 16 + c16;
    b1r[t] = b1g[col]; br1r[t] = br1g[col];
  }
  {
    int col = wv * 16 + c16;
    b2r = b2g[col]; br2r = br2g[col];
  }

  f4 s_;   // fp32 master state, C-layout: row=q*4+r, col=wv*16+c16
  s_ = (f4){0.f, 0.f, 0.f, 0.f};
  f4 sacc = s_;

  // write state into X plane as fp16 hi/lo pair
  auto write_state_x = [&](const f4& v) {
#pragma unroll
    for (int r = 0; r < 4; ++r) {
      float x = v[r];
      _Float16 hi = (_Float16)x;
      _Float16 lo = (_Float16)(x - (float)hi);
      int a = (q*4 + r) * XSTR + wv*16 + c16;
      sX[a] = hi;
      sX[a + 320] = lo;
    }
  };

  write_state_x(s_);   // initial state = 0
  __syncthreads();

  // ---- reverse scan: ti = T-1 .. 0.  For ti < T-1 run the 12 RK4 ode steps of
  // interval [ti, ti+1] first, then the rnn update at ti.  Single inline copy
  // of each eval type => hot body fits L1 I-cache. ----
  for (int ti = TT - 1; ti >= 0; --ti) {
    if (ti < TT - 1) {
      float dt = ts[(size_t)b0 * TT + ti] - ts[(size_t)b0 * TT + ti + 1];
      float h = dt / 3.0f;   // N_SUB = 3
#pragma clang loop unroll(disable)
      for (int j = 0; j < 12; ++j) {
        int st = j & 3;
        if (st == 0) sacc = s_;
        // ---- ODE MLP eval: kk = tanh(X@W1+b1)@W2 + b2 (1 internal barrier) ----
        // Split accumulators: hi-plane and lo-plane chains independent (8-deep).
        f4 aA[2], aB[2];
#pragma unroll
        for (int t = 0; t < 2; ++t) {
          aA[t] = (f4){0.f, 0.f, 0.f, 0.f};
          aB[t] = (f4){0.f, 0.f, 0.f, 0.f};
        }
#pragma unroll
        for (int ks = 0; ks < 8; ++ks) {
          h8 ah = *(const h8*)(sX + c16 * XSTR + ks * 32 + q * 8);
          h8 al = *(const h8*)(sX + c16 * XSTR + 320 + ks * 32 + q * 8);
#pragma unroll
          for (int t = 0; t < 2; ++t) {
            aA[t] = __builtin_amdgcn_mfma_f32_16x16x32_f16(ah, w1f[t][ks], aA[t], 0, 0, 0);
            aB[t] = __builtin_amdgcn_mfma_f32_16x16x32_f16(al, w1f[t][ks], aB[t], 0, 0, 0);
          }
        }
#pragma unroll
        for (int t = 0; t < 2; ++t)
#pragma unroll
          for (int r = 0; r < 4; ++r)
            sH[(q*4 + r) * HSTR + wv*32 + t*16 + c16] =
                (_Float16)tanh_acc(aA[t][r] + aB[t][r] + b1r[t]);
        __syncthreads();   // sX reads done; sH visible
        // GEMM2: even/odd ks chains independent (8-deep each).
        f4 a2A = (f4){0.f, 0.f, 0.f, 0.f};
        f4 a2B = (f4){0.f, 0.f, 0.f, 0.f};
#pragma unroll
        for (int ks = 0; ks < 16; ks += 2) {
          h8 ah0 = *(const h8*)(sH + c16 * HSTR + ks * 32 + q * 8);
          h8 ah1 = *(const h8*)(sH + c16 * HSTR + (ks + 1) * 32 + q * 8);
          a2A = __builtin_amdgcn_mfma_f32_16x16x32_f16(ah0, w2f[ks], a2A, 0, 0, 0);
          a2B = __builtin_amdgcn_mfma_f32_16x16x32_f16(ah1, w2f[ks + 1], a2B, 0, 0, 0);
        }
        // ---- RK4 update (wave-uniform st branches) ----
        float caS = (st == 0 || st == 3) ? h * (1.0f / 6.0f) : h * (1.0f / 3.0f);
        f4 kk, xv;
#pragma unroll
        for (int r = 0; r < 4; ++r) {
          kk[r] = a2A[r] + a2B[r] + b2r;
          sacc[r] += caS * kk[r];
        }
        if (st < 3) {
          float cxv = (st == 2) ? h : 0.5f * h;
#pragma unroll
          for (int r = 0; r < 4; ++r)
            xv[r] = s_[r] + cxv * kk[r];
        } else {
          s_ = sacc;
          xv = s_;
        }
        write_state_x(xv);
        __syncthreads();
      }
    }
    // ---- RNN update: s += tanh([s,x]@Wr1+br1)@Wr2 + br2 (Wr hi+lo from L2) ----
    {
      int row = tid >> 6, col = tid & 63;    // 1024 threads: 1 elem each
      float x0 = dataset[((size_t)(b0 + row) * TT + ti) * OBS + col];
      _Float16 hi = (_Float16)x0;
      sX[row * XSTR + 256 + col] = hi;
      sX[row * XSTR + 576 + col] = (_Float16)(x0 - (float)hi);
    }
    __syncthreads();                         // obs + state visible
    {
      // GEMM1: 3-way split accumulators (ah*bh, ah*bl, al*bh), 10-deep chains.
      f4 rA[2], rB[2], rC[2];
#pragma unroll
      for (int t = 0; t < 2; ++t) {
        rA[t] = (f4){0.f, 0.f, 0.f, 0.f};
        rB[t] = (f4){0.f, 0.f, 0.f, 0.f};
        rC[t] = (f4){0.f, 0.f, 0.f, 0.f};
      }
#pragma clang loop unroll(disable)
      for (int ks = 0; ks < 10; ++ks) {      // runtime loop: streamed weights
        h8 ah = *(const h8*)(sX + c16 * XSTR + ks * 32 + q * 8);
        h8 al = *(const h8*)(sX + c16 * XSTR + 320 + ks * 32 + q * 8);
#pragma unroll
        for (int t = 0; t < 2; ++t) {
          unsigned fi = (unsigned)(((ks*32 + wv*2 + t)*64 + ln) * 8);
          h8 bfh = *(const h8*)(ws + OFF_WR1 + fi);
          h8 bfl = *(const h8*)(ws + OFF_WR1L + fi);
          rA[t] = __builtin_amdgcn_mfma_f32_16x16x32_f16(ah, bfh, rA[t], 0, 0, 0);
          rB[t] = __builtin_amdgcn_mfma_f32_16x16x32_f16(ah, bfl, rB[t], 0, 0, 0);
          rC[t] = __builtin_amdgcn_mfma_f32_16x16x32_f16(al, bfh, rC[t], 0, 0, 0);
        }
      }
      // hidden hi+lo planes written together, single barrier (de-aliased sHL)
#pragma unroll
      for (int t = 0; t < 2; ++t)
#pragma unroll
        for (int r = 0; r < 4; ++r) {
          float v = tanh_acc(rA[t][r] + rB[t][r] + rC[t][r] + br1r[t]);
          _Float16 hi = (_Float16)v;
          int a = (q*4 + r) * HSTR + wv*32 + t*16 + c16;
          sH[a] = hi;
          sHL[a] = (_Float16)(v - (float)hi);
        }
      __syncthreads();   // all waves done reading sX; sH/sHL visible
      // GEMM2: 3-way split accumulators, 16-deep chains.
      f4 gA = (f4){0.f, 0.f, 0.f, 0.f};
      f4 gB = (f4){0.f, 0.f, 0.f, 0.f};
      f4 gC = (f4){0.f, 0.f, 0.f, 0.f};
#pragma clang loop unroll(disable)
      for (int ks = 0; ks < 16; ++ks) {      // runtime loop: streamed weights
        h8 ah = *(const h8*)(sH + c16 * HSTR + ks * 32 + q * 8);
        h8 al = *(const h8*)(sHL + c16 * HSTR + ks * 32 + q * 8);
        unsigned fi = (unsigned)(((ks*16 + wv)*64 + ln) * 8);
        h8 bfh = *(const h8*)(ws + OFF_WR2 + fi);
        h8 bfl = *(const h8*)(ws + OFF_WR2L + fi);
        gA = __builtin_amdgcn_mfma_f32_16x16x32_f16(ah, bfh, gA, 0, 0, 0);
        gB = __builtin_amdgcn_mfma_f32_16x16x32_f16(al, bfh, gB, 0, 0, 0);
        gC = __builtin_amdgcn_mfma_f32_16x16x32_f16(ah, bfl, gC, 0, 0, 0);
      }
#pragma unroll
      for (int r = 0; r < 4; ++r)
        s_[r] += gA[r] + gB[r] + gC[r] + br2r;
      write_state_x(s_);   // GEMM1 of next step reads sX only after barrier
      __syncthreads();
    }
  }

  // ---- store final state (fp32) ----
#pragma unroll
  for (int r = 0; r < 4; ++r)
    out[(size_t)(b0 + q*4 + r) * LATENT + wv*16 + c16] = s_[r];
}

extern "C" void kernel_launch(void* const* d_in, const int* in_sizes, int n_in,
                              void* d_out, int out_size, void* d_ws, size_t ws_size,
                              hipStream_t stream) {
  const float* dataset = (const float*)d_in[0];
  const float* ts  = (const float*)d_in[1];
  const float* W1  = (const float*)d_in[2];
  const float* b1  = (const float*)d_in[3];
  const float* W2  = (const float*)d_in[4];
  const float* b2  = (const float*)d_in[5];
  const float* Wr1 = (const float*)d_in[6];
  const float* br1 = (const float*)d_in[7];
  const float* Wr2 = (const float*)d_in[8];
  const float* br2 = (const float*)d_in[9];
  _Float16* ws = (_Float16*)d_ws;

  prep_kernel<<<416, 256, 0, stream>>>(W1, W2, Wr1, Wr2, ws);

  (void)hipFuncSetAttribute((const void*)ode_main,
                            hipFuncAttributeMaxDynamicSharedMemorySize, LDS_TOTAL);
  ode_main<<<16, 1024, LDS_TOTAL, stream>>>(dataset, ts, b1, b2, br1, br2, ws,
                                            (float*)d_out);
}

// Round 3
// 7852.392 us; speedup vs baseline: 1.4769x; 1.4769x over previous
//
#include <hip/hip_runtime.h>

// RecognitionODERNN: B=256,T=96,OBS=64,LATENT=256,HID=512, 3 RK4 substeps/interval.
// 16 persistent workgroups (one per CU), 16 batch rows each, no inter-WG sync.
// fp16 MFMA 16x16x32, fp32 accumulate, fp32 master state; accurate tanh (~1 ulp).
// R10: runtime 12-step RK4 loop, single rnn call site => hot body fits L1I.
// R11: 16 waves NEUTRAL (lockstep; LDS traffic scales with waves). R12: W2 fully
// reg-resident at 4 waves/EU REGRESSED (scratch spills: WRITE_SIZE 2x).
// R13 (this): back to 512 thr / 2 waves per EU (256-VGPR budget), R0 weight split
// (W2 = 9 reg groups + 7 LDS groups). Counters say all pipes <=36% busy yet eval
// = ~13k cyc @2.4GHz => ~6.5k cyc exposed latency. Attack:
//   (a) explicit register PREFETCH of all A-fragments per GEMM phase (batch the
//       ~120cyc LDS latency once per phase; 2-wave/EU budget has the VGPRs now);
//   (b) accumulator chain split: GEMM1 hi/lo (8 chains/wave), GEMM2 even/odd ks
//       (4 chains), RNN 3-way (clean retest of R12's idea, no spills);
//   (c) tanh IEEE-div -> v_rcp + 1 Newton iteration (~1 ulp kept).

#define TT 96
#define OBS 64
#define LATENT 256
#define HID 512

typedef _Float16 h8 __attribute__((ext_vector_type(8)));
typedef _Float16 h2 __attribute__((ext_vector_type(2)));
typedef float f4 __attribute__((ext_vector_type(4)));

// ws layout (fp16 element offsets), all regions in MFMA B-fragment order.
#define OFF_W1F   0u        // [w(8)][t(4)][ks(8)][lane(64)][j(8)]   W1 256x512 hi
#define OFF_W2V   131072u   // [w(8)][t2(2)][ks(8)][lane][j]         W2 k=0..255 hi
#define OFF_W2L   196608u   // [ks2(8)][w(8)][t2(2)][lane][j]        W2 k=256..511 hi
#define OFF_WR1   262144u   // [ks(10)][w(8)][t(4)][lane][j]         Wr1 320x512 hi
#define OFF_WR2   425984u   // [ks(16)][w(8)][t2(2)][lane][j]        Wr2 512x256 hi
#define OFF_WR1L  557056u   // Wr1 lo plane (same geometry as hi)
#define OFF_WR2L  720896u   // Wr2 lo plane

// LDS layout (bytes): sW2 112 KB (W2-hi ks-groups 9..15), then activations.
#define LDS_X     114688
#define XSTR      648       // sX rows: [0,256) s-hi, [256,320) obs-hi,
                            //          [320,576) s-lo, [576,640) obs-lo, pad 8
#define LDS_H     (114688 + 16*XSTR*2)   // 135424
#define HSTR      520       // sH: 16 x 520 fp16 rows
#define LDS_TOTAL (135424 + 16*HSTR*2)   // 152064 <= 163840
// rnn hidden-lo plane aliases into sX (16 rows @ HSTR = 8312 elems <= 16*648).

__global__ void prep_kernel(const float* __restrict__ W1, const float* __restrict__ W2,
                            const float* __restrict__ Wr1, const float* __restrict__ Wr2,
                            _Float16* __restrict__ ws) {
  unsigned f = blockIdx.x * 256u + threadIdx.x;   // fragment id, 106496 total
  if (f >= 106496u) return;
  bool lo = false;
  unsigned fe = f, dstv = 0;
  if (f >= 90112u)      { lo = true; fe = f - 90112u + 53248u; dstv = OFF_WR2L + (f - 90112u) * 8u; }
  else if (f >= 69632u) { lo = true; fe = f - 69632u + 32768u; dstv = OFF_WR1L + (f - 69632u) * 8u; }
  const float* src;
  unsigned k0, n, ldn, dst;
  if (fe < 16384u) {                       // W1 frags
    unsigned ln = fe & 63u, ks = (fe >> 6) & 7u, t = (fe >> 9) & 3u, w = fe >> 11;
    n = w * 64u + t * 16u + (ln & 15u);
    k0 = ks * 32u + (ln >> 4) * 8u;
    src = W1; ldn = HID; dst = OFF_W1F + fe * 8u;
  } else if (fe < 24576u) {                // W2 k=0..255 (VGPR-resident)
    unsigned f2 = fe - 16384u;
    unsigned ln = f2 & 63u, ks = (f2 >> 6) & 7u, t2 = (f2 >> 9) & 1u, w = f2 >> 10;
    n = w * 32u + t2 * 16u + (ln & 15u);
    k0 = ks * 32u + (ln >> 4) * 8u;
    src = W2; ldn = LATENT; dst = OFF_W2V + f2 * 8u;
  } else if (fe < 32768u) {                // W2 k=256..511 (1 group VGPR + 7 LDS)
    unsigned f3 = fe - 24576u;
    unsigned ln = f3 & 63u, t2 = (f3 >> 6) & 1u, w = (f3 >> 7) & 7u, ks2 = f3 >> 10;
    n = w * 32u + t2 * 16u + (ln & 15u);
    k0 = (ks2 + 8u) * 32u + (ln >> 4) * 8u;
    src = W2; ldn = LATENT; dst = OFF_W2L + f3 * 8u;
  } else if (fe < 53248u) {                // Wr1 (streamed)
    unsigned f4_ = fe - 32768u;
    unsigned ln = f4_ & 63u, t = (f4_ >> 6) & 3u, w = (f4_ >> 8) & 7u, ks = f4_ >> 11;
    n = w * 64u + t * 16u + (ln & 15u);
    k0 = ks * 32u + (ln >> 4) * 8u;
    src = Wr1; ldn = HID; dst = OFF_WR1 + f4_ * 8u;
  } else {                                 // Wr2 (streamed)
    unsigned f5 = fe - 53248u;
    unsigned ln = f5 & 63u, t2 = (f5 >> 6) & 1u, w = (f5 >> 7) & 7u, ks = f5 >> 10;
    n = w * 32u + t2 * 16u + (ln & 15u);
    k0 = ks * 32u + (ln >> 4) * 8u;
    src = Wr2; ldn = LATENT; dst = OFF_WR2 + f5 * 8u;
  }
  if (lo) dst = dstv;
  h8 v;
#pragma unroll
  for (int j = 0; j < 8; ++j) {
    float w = src[(k0 + (unsigned)j) * ldn + n];
    _Float16 hi = (_Float16)w;
    v[j] = lo ? (_Float16)(w - (float)hi) : hi;
  }
  *(h8*)(ws + dst) = v;
}

// ~1 ulp tanh: Taylor (odd, to x^9) for |x|<0.25; exp2 + rcp+Newton above.
__device__ __forceinline__ float tanh_acc(float x) {
  float ax = __builtin_fabsf(x);
  float e = __builtin_amdgcn_exp2f(ax * -2.885390043258667f);   // e^-2x
  float den = 1.0f + e;
  float r0 = __builtin_amdgcn_rcpf(den);
  r0 = r0 * (2.0f - den * r0);               // Newton: ~0.5 ulp reciprocal
  float tl = (1.0f - e) * r0;
  float x2 = ax * ax;
  float p = -17.0f/315.0f + x2 * (62.0f/2835.0f);
  p = 2.0f/15.0f + x2 * p;
  p = -1.0f/3.0f + x2 * p;
  float ts = ax + (ax * x2) * p;
  float r = ax < 0.25f ? ts : tl;
  return __builtin_copysignf(r, x);
}

__global__ __launch_bounds__(512)
__attribute__((amdgpu_waves_per_eu(2, 2)))
void ode_main(
    const float* __restrict__ dataset, const float* __restrict__ ts,
    const float* __restrict__ b1g, const float* __restrict__ b2g,
    const float* __restrict__ br1g, const float* __restrict__ br2g,
    const _Float16* __restrict__ ws, float* __restrict__ out) {
  extern __shared__ char smem[];
  _Float16* sW2 = (_Float16*)(smem);            // 112 KB: W2-hi ks-groups 9..15
  _Float16* sX  = (_Float16*)(smem + LDS_X);
  _Float16* sH  = (_Float16*)(smem + LDS_H);

  const int tid = threadIdx.x;
  const int wv = tid >> 6, ln = tid & 63;
  const int q = ln >> 4, c16 = ln & 15;
  const int b0 = blockIdx.x * 16;

  // ---- resident weight fragments (registers): W1 all (128), W2 ks 0..8 (72) ----
  h8 w1f[4][8], w2f[2][9];
#pragma unroll
  for (int t = 0; t < 4; ++t)
#pragma unroll
    for (int ks = 0; ks < 8; ++ks)
      w1f[t][ks] = *(const h8*)(ws + OFF_W1F + (unsigned)((((wv*4 + t)*8 + ks)*64 + ln) * 8));
#pragma unroll
  for (int t2 = 0; t2 < 2; ++t2) {
#pragma unroll
    for (int ks = 0; ks < 8; ++ks)
      w2f[t2][ks] = *(const h8*)(ws + OFF_W2V + (unsigned)((((wv*2 + t2)*8 + ks)*64 + ln) * 8));
    w2f[t2][8] = *(const h8*)(ws + OFF_W2L + (unsigned)((wv*128 + t2*64 + ln) * 8));
  }

  // ---- stage W2-hi ks-groups 9..15 into LDS: 7 x 1024 frags from frag 1024 ----
  for (int it = 0; it < 14; ++it) {
    unsigned idx = (unsigned)(it * 512 + tid);
    *(h8*)(sW2 + idx * 8u) = *(const h8*)(ws + OFF_W2L + (1024u + idx) * 8u);
  }

  // ---- biases ----
  float b1r[4], br1r[4], b2r[2], br2r[2];
#pragma unroll
  for (int t = 0; t < 4; ++t) {
    int col = wv * 64 + t * 16 + c16;
    b1r[t] = b1g[col]; br1r[t] = br1g[col];
  }
#pragma unroll
  for (int t2 = 0; t2 < 2; ++t2) {
    int col = wv * 32 + t2 * 16 + c16;
    b2r[t2] = b2g[col]; br2r[t2] = br2g[col];
  }
  __syncthreads();

  f4 s_[2];   // fp32 master state, C-layout: row=q*4+r, col=wv*32+t2*16+c16
  s_[0] = (f4){0.f, 0.f, 0.f, 0.f};
  s_[1] = (f4){0.f, 0.f, 0.f, 0.f};
  f4 sacc[2];
  sacc[0] = s_[0]; sacc[1] = s_[1];

  // write state into X plane as fp16 hi/lo pair
  auto write_state_x = [&](const f4* v) {
#pragma unroll
    for (int t2 = 0; t2 < 2; ++t2)
#pragma unroll
      for (int r = 0; r < 4; ++r) {
        float x = v[t2][r];
        _Float16 hi = (_Float16)x;
        _Float16 lo = (_Float16)(x - (float)hi);
        int a = (q*4 + r) * XSTR + wv*32 + t2*16 + c16;
        sX[a] = hi;
        sX[a + 320] = lo;
      }
  };

  write_state_x(s_);   // initial state = 0

  // ---- reverse scan: ti = T-1 .. 0 ----
  for (int ti = TT - 1; ti >= 0; --ti) {
    if (ti < TT - 1) {
      float dt = ts[(size_t)b0 * TT + ti] - ts[(size_t)b0 * TT + ti + 1];
      float h = dt / 3.0f;   // N_SUB = 3
#pragma clang loop unroll(disable)
      for (int j = 0; j < 12; ++j) {
        int st = j & 3;
        if (st == 0) { sacc[0] = s_[0]; sacc[1] = s_[1]; }
        // ---- ODE MLP eval: kk = tanh(X@W1+b1)@W2 + b2 (1 internal barrier) ----
        // Prefetch ALL A-fragments (hi+lo) into registers first: batches the
        // LDS latency once; then 64 MFMAs run back-to-back.
        h8 xah[8], xal[8];
#pragma unroll
        for (int ks = 0; ks < 8; ++ks) {
          xah[ks] = *(const h8*)(sX + c16 * XSTR + ks * 32 + q * 8);
          xal[ks] = *(const h8*)(sX + c16 * XSTR + 320 + ks * 32 + q * 8);
        }
        // Chain split: hi-plane (aA) and lo-plane (aB) accumulate independently.
        f4 aA[4], aB[4];
#pragma unroll
        for (int t = 0; t < 4; ++t) {
          aA[t] = (f4){0.f, 0.f, 0.f, 0.f};
          aB[t] = (f4){0.f, 0.f, 0.f, 0.f};
        }
#pragma unroll
        for (int ks = 0; ks < 8; ++ks)
#pragma unroll
          for (int t = 0; t < 4; ++t) {
            aA[t] = __builtin_amdgcn_mfma_f32_16x16x32_f16(xah[ks], w1f[t][ks], aA[t], 0, 0, 0);
            aB[t] = __builtin_amdgcn_mfma_f32_16x16x32_f16(xal[ks], w1f[t][ks], aB[t], 0, 0, 0);
          }
#pragma unroll
        for (int t = 0; t < 4; ++t)
#pragma unroll
          for (int r = 0; r < 4; ++r)
            sH[(q*4 + r) * HSTR + wv*64 + t*16 + c16] =
                (_Float16)tanh_acc(aA[t][r] + aB[t][r] + b1r[t]);
        __syncthreads();   // sX reads done; sH visible
        // GEMM2: prefetch all 16 H-fragments, even/odd-ks chain split per t2.
        h8 hh[16];
#pragma unroll
        for (int ks = 0; ks < 16; ++ks)
          hh[ks] = *(const h8*)(sH + c16 * HSTR + ks * 32 + q * 8);
        f4 a2A[2], a2B[2];
#pragma unroll
        for (int t2 = 0; t2 < 2; ++t2) {
          a2A[t2] = (f4){0.f, 0.f, 0.f, 0.f};
          a2B[t2] = (f4){0.f, 0.f, 0.f, 0.f};
        }
#pragma unroll
        for (int ks = 0; ks < 16; ks += 2) {
#pragma unroll
          for (int t2 = 0; t2 < 2; ++t2) {
            h8 bf0, bf1;
            if (ks <= 8)     bf0 = w2f[t2][ks];
            else             bf0 = *(const h8*)(sW2 + (unsigned)((((ks - 9)*16 + wv*2 + t2)*64 + ln) * 8));
            if (ks + 1 <= 8) bf1 = w2f[t2][ks + 1];
            else             bf1 = *(const h8*)(sW2 + (unsigned)((((ks - 8)*16 + wv*2 + t2)*64 + ln) * 8));
            a2A[t2] = __builtin_amdgcn_mfma_f32_16x16x32_f16(hh[ks], bf0, a2A[t2], 0, 0, 0);
            a2B[t2] = __builtin_amdgcn_mfma_f32_16x16x32_f16(hh[ks + 1], bf1, a2B[t2], 0, 0, 0);
          }
        }
        // ---- RK4 update (wave-uniform st branches) ----
        float caS = (st == 0 || st == 3) ? h * (1.0f / 6.0f) : h * (1.0f / 3.0f);
        f4 kk[2], xv[2];
#pragma unroll
        for (int t2 = 0; t2 < 2; ++t2)
#pragma unroll
          for (int r = 0; r < 4; ++r) {
            kk[t2][r] = a2A[t2][r] + a2B[t2][r] + b2r[t2];
            sacc[t2][r] += caS * kk[t2][r];
          }
        if (st < 3) {
          float cxv = (st == 2) ? h : 0.5f * h;
#pragma unroll
          for (int t2 = 0; t2 < 2; ++t2)
#pragma unroll
            for (int r = 0; r < 4; ++r)
              xv[t2][r] = s_[t2][r] + cxv * kk[t2][r];
        } else {
          s_[0] = sacc[0]; s_[1] = sacc[1];
          xv[0] = s_[0]; xv[1] = s_[1];
        }
        write_state_x(xv);
        __syncthreads();
      }
    }
    // ---- RNN update: s += tanh([s,x]@Wr1+br1)@Wr2 + br2 (Wr hi+lo from L2) ----
    {
      int row = tid >> 5, col2 = (tid & 31) * 2;
      const float* dp = dataset + ((size_t)(b0 + row) * TT + ti) * OBS + col2;
      float x0 = dp[0], x1 = dp[1];
      h2 xh, xl;
      xh[0] = (_Float16)x0; xh[1] = (_Float16)x1;
      xl[0] = (_Float16)(x0 - (float)xh[0]);
      xl[1] = (_Float16)(x1 - (float)xh[1]);
      *(h2*)(sX + row * XSTR + 256 + col2) = xh;
      *(h2*)(sX + row * XSTR + 576 + col2) = xl;
    }
    __syncthreads();
    {
      // GEMM1: 3-way split accumulators (ah*bh, ah*bl, al*bh), 10-deep chains.
      f4 rA[4], rB[4], rC[4];
#pragma unroll
      for (int t = 0; t < 4; ++t) {
        rA[t] = (f4){0.f, 0.f, 0.f, 0.f};
        rB[t] = (f4){0.f, 0.f, 0.f, 0.f};
        rC[t] = (f4){0.f, 0.f, 0.f, 0.f};
      }
#pragma clang loop unroll(disable)
      for (int ks = 0; ks < 10; ++ks) {      // runtime loop: streamed weights
        h8 ah = *(const h8*)(sX + c16 * XSTR + ks * 32 + q * 8);
        h8 al = *(const h8*)(sX + c16 * XSTR + 320 + ks * 32 + q * 8);
#pragma unroll
        for (int t = 0; t < 4; ++t) {
          unsigned fi = (unsigned)((((ks*8 + wv)*4 + t)*64 + ln) * 8);
          h8 bfh = *(const h8*)(ws + OFF_WR1 + fi);
          h8 bfl = *(const h8*)(ws + OFF_WR1L + fi);
          rA[t] = __builtin_amdgcn_mfma_f32_16x16x32_f16(ah, bfh, rA[t], 0, 0, 0);
          rB[t] = __builtin_amdgcn_mfma_f32_16x16x32_f16(ah, bfl, rB[t], 0, 0, 0);
          rC[t] = __builtin_amdgcn_mfma_f32_16x16x32_f16(al, bfh, rC[t], 0, 0, 0);
        }
      }
      f4 th[4];
#pragma unroll
      for (int t = 0; t < 4; ++t)
#pragma unroll
        for (int r = 0; r < 4; ++r) {
          float v = tanh_acc(rA[t][r] + rB[t][r] + rC[t][r] + br1r[t]);
          th[t][r] = v;
          sH[(q*4 + r) * HSTR + wv*64 + t*16 + c16] = (_Float16)v;
        }
      __syncthreads();   // all waves done reading sX; sH-hi visible
#pragma unroll
      for (int t = 0; t < 4; ++t)
#pragma unroll
        for (int r = 0; r < 4; ++r) {
          float v = th[t][r];
          _Float16 hi = (_Float16)v;
          sX[(q*4 + r) * HSTR + wv*64 + t*16 + c16] = (_Float16)(v - (float)hi);
        }
      __syncthreads();   // h-lo plane (X alias) visible
      // GEMM2: 3-way split accumulators per t2 (6 chains), streamed weights.
      f4 gA[2], gB[2], gC[2];
#pragma unroll
      for (int t2 = 0; t2 < 2; ++t2) {
        gA[t2] = (f4){0.f, 0.f, 0.f, 0.f};
        gB[t2] = (f4){0.f, 0.f, 0.f, 0.f};
        gC[t2] = (f4){0.f, 0.f, 0.f, 0.f};
      }
#pragma clang loop unroll(disable)
      for (int ks = 0; ks < 16; ++ks) {      // runtime loop: streamed weights
        h8 ah = *(const h8*)(sH + c16 * HSTR + ks * 32 + q * 8);
        h8 al = *(const h8*)(sX + c16 * HSTR + ks * 32 + q * 8);
#pragma unroll
        for (int t2 = 0; t2 < 2; ++t2) {
          unsigned fi = (unsigned)((((ks*8 + wv)*2 + t2)*64 + ln) * 8);
          h8 bfh = *(const h8*)(ws + OFF_WR2 + fi);
          h8 bfl = *(const h8*)(ws + OFF_WR2L + fi);
          gA[t2] = __builtin_amdgcn_mfma_f32_16x16x32_f16(ah, bfh, gA[t2], 0, 0, 0);
          gB[t2] = __builtin_amdgcn_mfma_f32_16x16x32_f16(al, bfh, gB[t2], 0, 0, 0);
          gC[t2] = __builtin_amdgcn_mfma_f32_16x16x32_f16(ah, bfl, gC[t2], 0, 0, 0);
        }
      }
      __syncthreads();   // all X-alias reads done before X rewrite
#pragma unroll
      for (int t2 = 0; t2 < 2; ++t2)
#pragma unroll
        for (int r = 0; r < 4; ++r)
          s_[t2][r] += gA[t2][r] + gB[t2][r] + gC[t2][r] + br2r[t2];
      write_state_x(s_);
      __syncthreads();
    }
  }

  // ---- store final state (fp32) ----
#pragma unroll
  for (int t2 = 0; t2 < 2; ++t2)
#pragma unroll
    for (int r = 0; r < 4; ++r)
      out[(size_t)(b0 + q*4 + r) * LATENT + wv*32 + t2*16 + c16] = s_[t2][r];
}

extern "C" void kernel_launch(void* const* d_in, const int* in_sizes, int n_in,
                              void* d_out, int out_size, void* d_ws, size_t ws_size,
                              hipStream_t stream) {
  const float* dataset = (const float*)d_in[0];
  const float* ts  = (const float*)d_in[1];
  const float* W1  = (const float*)d_in[2];
  const float* b1  = (const float*)d_in[3];
  const float* W2  = (const float*)d_in[4];
  const float* b2  = (const float*)d_in[5];
  const float* Wr1 = (const float*)d_in[6];
  const float* br1 = (const float*)d_in[7];
  const float* Wr2 = (const float*)d_in[8];
  const float* br2 = (const float*)d_in[9];
  _Float16* ws = (_Float16*)d_ws;

  prep_kernel<<<416, 256, 0, stream>>>(W1, W2, Wr1, Wr2, ws);

  (void)hipFuncSetAttribute((const void*)ode_main,
                            hipFuncAttributeMaxDynamicSharedMemorySize, LDS_TOTAL);
  ode_main<<<16, 512, LDS_TOTAL, stream>>>(dataset, ts, b1, b2, br1, br2, ws,
                                           (float*)d_out);
}